// Round 10
// baseline (278.519 us; speedup 1.0000x reference)
//
#include <hip/hip_runtime.h>

#define NN 4096
#define DD 512
#define FF 512
#define HH 4
#define KK 1024   // concat GEMM depth

typedef _Float16 f16;
typedef f16 f16x8 __attribute__((ext_vector_type(8)));
typedef f16 f16x4 __attribute__((ext_vector_type(4)));
typedef float f32x4 __attribute__((ext_vector_type(4)));
typedef float f32x16 __attribute__((ext_vector_type(16)));

// ---------------- async global->LDS (16 B per lane; LDS dest = uniform base + lane*16) ----------------
typedef __attribute__((address_space(1))) void gvoid;
typedef __attribute__((address_space(3))) void svoid;
__device__ __forceinline__ void glds16(const void* g, void* s) {
    __builtin_amdgcn_global_load_lds((gvoid*)g, (svoid*)s, 16, 0, 0);
}

// ---------------- static device workspace (fully rewritten every call) ----------------
__device__ __attribute__((aligned(16))) f16 g_catA[NN * KK];         //  8 MB  [n][ nodes(512) | X(512) ]
__device__ __attribute__((aligned(16))) f16 g_catB[HH * FF * KK];    //  4 MB  [h][f][ W_h^T(512) | We^T(512) ]
__device__ __attribute__((aligned(16))) f16 g_featsH[HH * FF * NN];  // 16 MB  (feats+e)^T
__device__ __attribute__((aligned(16))) f16 g_oaccH[(size_t)2 * HH * NN * FF]; // 33.5 MB f16 partial slabs
__device__ float g_Zp[2 * HH * NN];                                  // per-(h,ks) row weight-sums
__device__ float g_bcat[HH * FF];                                    // b_h[f] + be[f]
__device__ float g_tu[HH * DD], g_tv[HH * DD], g_bu[HH], g_bv[HH];
__device__ float g_p[HH * NN], g_q[HH * NN];

#define PREP_CONV 4104    // (2*NN*DD/4 + HH*FF) / 256 blocks
#define PREP_TRAN 320
#define PREP_UV   513

// ---------------- fused prep: fp32->f16 concat staging (vectorized) + transposes + u/v proj ----------------
__global__ __launch_bounds__(256) void k_prep(const float* __restrict__ nodes, const float* __restrict__ edges,
                                              const float* __restrict__ labels, const float* __restrict__ We,
                                              const float* __restrict__ W, const float* __restrict__ be,
                                              const float* __restrict__ b, const float* __restrict__ u,
                                              const float* __restrict__ v) {
    __shared__ float lds[64 * 65];
    int bx = blockIdx.x;
    int tid = threadIdx.x;
    if (bx < PREP_CONV) {
        int id = bx * 256 + tid;
        const int NQ = NN * DD / 4;              // 524288 float4 groups
        if (id < NQ) {                           // nodes -> catA[:, 0:512]
            f32x4 vv = *(const f32x4*)(nodes + (size_t)id * 4);
            f16x4 ov;
#pragma unroll
            for (int k = 0; k < 4; ++k) ov[k] = (f16)vv[k];
            *(f16x4*)&g_catA[(size_t)(id >> 7) * KK + (id & 127) * 4] = ov;
            return;
        }
        id -= NQ;
        if (id < NQ) {                           // edges+labels -> catA[:, 512:1024]
            f32x4 ev = *(const f32x4*)(edges  + (size_t)id * 4);
            f32x4 lv = *(const f32x4*)(labels + (size_t)id * 4);
            f16x4 ov;
#pragma unroll
            for (int k = 0; k < 4; ++k) ov[k] = (f16)(ev[k] + lv[k]);
            *(f16x4*)&g_catA[(size_t)(id >> 7) * KK + 512 + (id & 127) * 4] = ov;
            return;
        }
        id -= NQ;
        if (id < HH * FF) { g_bcat[id] = b[id] + be[id & 511]; return; }
        return;
    }
    if (bx < PREP_CONV + PREP_TRAN) {
        int bid = bx - PREP_CONV;                    // 0..319
        int mi = bid >> 6;                           // 0 = We, 1..4 = W head
        int t64 = bid & 63;
        const float* src = (mi == 0) ? We : (W + (size_t)(mi - 1) * DD * FF);
        int ti = t64 >> 3, tj = t64 & 7;             // 64x64 tile coords in [d][f]
        int r = tid >> 2, cseg = (tid & 3) * 16;
#pragma unroll
        for (int kq = 0; kq < 4; ++kq) {
            f32x4 vv = *(const f32x4*)(src + (size_t)(ti * 64 + r) * 512 + tj * 64 + cseg + kq * 4);
            *(f32x4*)&lds[r * 65 + cseg + kq * 4] = vv;
        }
        __syncthreads();
        int fl = tid >> 2, dseg = (tid & 3) * 16;
        f16x8 o0, o1;
#pragma unroll
        for (int k = 0; k < 8; ++k) o0[k] = (f16)lds[(dseg + k) * 65 + fl];
#pragma unroll
        for (int k = 0; k < 8; ++k) o1[k] = (f16)lds[(dseg + 8 + k) * 65 + fl];
        size_t frow = (size_t)(tj * 64 + fl);
        size_t dcol = (size_t)(ti * 64 + dseg);
        if (mi == 0) {                               // We^T -> every head's [512:1024] slice
#pragma unroll
            for (int hh = 0; hh < HH; ++hh) {
                size_t ob = ((size_t)hh * FF + frow) * KK + 512 + dcol;
                *(f16x8*)&g_catB[ob] = o0;
                *(f16x8*)&g_catB[ob + 8] = o1;
            }
        } else {                                     // W_h^T -> head's [0:512] slice
            size_t ob = ((size_t)(mi - 1) * FF + frow) * KK + dcol;
            *(f16x8*)&g_catB[ob] = o0;
            *(f16x8*)&g_catB[ob + 8] = o1;
        }
        return;
    }
    {
        int row = (bx - PREP_CONV - PREP_TRAN) * 4 + (tid >> 6);   // 2052 rows
        int lane = tid & 63;
        float su = 0.f, sv = 0.f;
        if (row < HH * DD) {
            int h = row >> 9, d = row & 511;
            size_t wb = (size_t)h * DD * FF + (size_t)d * FF;
#pragma unroll
            for (int j = 0; j < 8; ++j) {
                int f = lane + 64 * j;
                float wv = W[wb + f];
                su += wv * u[(size_t)h * FF + f];
                sv += wv * v[(size_t)h * FF + f];
            }
        } else if (row < HH * DD + HH) {
            int h = row - HH * DD;
#pragma unroll
            for (int j = 0; j < 8; ++j) {
                int f = lane + 64 * j;
                float bvv = b[(size_t)h * FF + f];
                su += bvv * u[(size_t)h * FF + f];
                sv += bvv * v[(size_t)h * FF + f];
            }
        }
#pragma unroll
        for (int m = 1; m < 64; m <<= 1) {
            su += __shfl_xor(su, m, 64);
            sv += __shfl_xor(sv, m, 64);
        }
        if (lane == 0 && row < HH * DD + HH) {
            if (row < HH * DD) { g_tu[row] = su; g_tv[row] = sv; }
            else { g_bu[row - HH * DD] = su; g_bv[row - HH * DD] = sv; }
        }
    }
}

// ---------------- p[h][n] = nodes[n].t_u[h] + bu[h];  q likewise (vectorized loads) ----------------
__global__ __launch_bounds__(256) void k_pq() {
    int row = blockIdx.x * 4 + (threadIdx.x >> 6);    // 4096 blocks -> 16384 rows = H*N
    int lane = threadIdx.x & 63;
    int h = row >> 12, n = row & 4095;
    const f16* nb = g_catA + (size_t)n * KK + lane * 8;   // nodes slice, 8 contiguous d's per lane
    const float* tu = g_tu + h * DD + lane * 8;
    const float* tv = g_tv + h * DD + lane * 8;
    f16x8 nv8 = *(const f16x8*)nb;
    f32x4 tu0 = *(const f32x4*)tu, tu1 = *(const f32x4*)(tu + 4);
    f32x4 tv0 = *(const f32x4*)tv, tv1 = *(const f32x4*)(tv + 4);
    float pa = 0.f, qa = 0.f;
#pragma unroll
    for (int j = 0; j < 4; ++j) {
        float nv = (float)nv8[j];
        pa += nv * tu0[j];
        qa += nv * tv0[j];
    }
#pragma unroll
    for (int j = 0; j < 4; ++j) {
        float nv = (float)nv8[4 + j];
        pa += nv * tu1[j];
        qa += nv * tv1[j];
    }
#pragma unroll
    for (int m = 1; m < 64; m <<= 1) {
        pa += __shfl_xor(pa, m, 64);
        qa += __shfl_xor(qa, m, 64);
    }
    if (lane == 0) {
        g_p[row] = pa + g_bu[h];
        g_q[row] = qa + g_bv[h];
    }
}

// ---------------- concat GEMM v3 (BK=128, 8 intervals): featsH[h][f][n] = f16(catA@catB^T + bcat)
//                  tile 128n x 128f, all-glds staging, 16-chunk XOR swizzle ----------------
__global__ __launch_bounds__(256, 2) void k_gemm_feats() {
    __shared__ f16 As[128 * 128];       // 32 KB  [n][k0..127], 256-B rows, chunk-swizzled
    __shared__ f16 Bs[128 * 128];       // 32 KB  [f][k0..127]
    int tid = threadIdx.x;
    int lane = tid & 63, wave = tid >> 6;        // 4 waves
    int wr = wave & 1, wc = wave >> 1;
    int c = lane & 15, g = lane >> 4;
    int n0 = blockIdx.x * 128, f0 = blockIdx.y * 128;
    int h = blockIdx.z;
    const f16* Bgl = g_catB + (size_t)h * FF * KK;
    int r4 = lane >> 4;                  // row within 4-row glds group (0..3)
    int ch = lane & 15;                  // chunk slot this lane fills (16 chunks of 16B per row)
    f32x4 acc[4][4] = {};
    for (int kk = 0; kk < KK; kk += 128) {
        __syncthreads();
#pragma unroll
        for (int j = 0; j < 8; ++j) {
            int rowb = wave * 32 + j * 4;        // wave stages rows [wave*32, wave*32+32)
            int row = rowb + r4;
            int src = (ch ^ (row & 15)) * 8;     // swizzled source k-chunk (f16 elems)
            glds16(g_catA + (size_t)(n0 + row) * KK + kk + src, &As[rowb * 128]);
            glds16(Bgl    + (size_t)(f0 + row) * KK + kk + src, &Bs[rowb * 128]);
        }
        __syncthreads();
#pragma unroll
        for (int s = 0; s < 4; ++s) {
            f16x8 af[4], bf[4];
#pragma unroll
            for (int i = 0; i < 4; ++i) {
                int ra = wr * 64 + i * 16 + c;
                af[i] = *(const f16x8*)&As[ra * 128 + (((s * 4 + g) ^ (ra & 15)) * 8)];
            }
#pragma unroll
            for (int jj = 0; jj < 4; ++jj) {
                int rb = wc * 64 + jj * 16 + c;
                bf[jj] = *(const f16x8*)&Bs[rb * 128 + (((s * 4 + g) ^ (rb & 15)) * 8)];
            }
#pragma unroll
            for (int i = 0; i < 4; ++i)
#pragma unroll
                for (int jj = 0; jj < 4; ++jj)
                    acc[i][jj] = __builtin_amdgcn_mfma_f32_16x16x32_f16(af[i], bf[jj], acc[i][jj], 0, 0, 0);
        }
    }
#pragma unroll
    for (int jj = 0; jj < 4; ++jj) {
        int f = f0 + wc * 64 + jj * 16 + c;
        float bv = g_bcat[h * FF + f];
#pragma unroll
        for (int i = 0; i < 4; ++i) {
            int r0 = n0 + wr * 64 + i * 16 + g * 4;
            f16x4 ov;
#pragma unroll
            for (int rr = 0; rr < 4; ++rr) ov[rr] = (f16)(acc[i][jj][rr] + bv);
            *(f16x4*)(g_featsH + ((size_t)h * FF + f) * NN + r0) = ov;
        }
    }
}

// ---------------- GEMM3 v9: occupancy-first. 256-thr/4-wave blocks, tile 64n x 256f,
//                  acc[2][2]=64 AGPR, launch_bounds(256,3) -> 3 independent blocks per SIMD.
//                  Keeps v8's proven parts: B direct-from-L2 (XCD-pinned), pad-68 As (0 conflicts),
//                  in-block M, single barrier/step. GEN+As duplicated x2 across f-halves (accepted). --------
#define WCALC(qv, dstvec, idx)                                              \
    {                                                                       \
        float s_ = pv * (qv);                                               \
        s_ = fmaxf(s_, 0.3f * s_);                                          \
        float e_ = __builtin_amdgcn_exp2f(__builtin_fmaf(s_, L2E, -mvb));   \
        zacc += e_;                                                         \
        dstvec[idx] = (f16)e_;                                              \
    }
#define GEN8(qa, qb, w)                                                     \
    {                                                                       \
        _Pragma("unroll") for (int k_ = 0; k_ < 4; ++k_) {                  \
            WCALC((qa)[k_], w, k_);                                         \
            WCALC((qb)[k_], w, 4 + k_);                                     \
        }                                                                   \
    }
// one sub-k: 2 af ds_reads + 4 MFMA against a B-frag pair
#define SKSTEP(skidx, bfa, bfb)                                             \
    {                                                                       \
        int cA_ = ((skidx) * 2 + h5) * 8;                                   \
        f16x8 af0 = *(const f16x8*)&As2[cur][(c5) * 68 + cA_];              \
        f16x8 af1 = *(const f16x8*)&As2[cur][(32 + c5) * 68 + cA_];         \
        acc[0][0] = __builtin_amdgcn_mfma_f32_32x32x16_f16(af0, bfa, acc[0][0], 0, 0, 0); \
        acc[0][1] = __builtin_amdgcn_mfma_f32_32x32x16_f16(af0, bfb, acc[0][1], 0, 0, 0); \
        acc[1][0] = __builtin_amdgcn_mfma_f32_32x32x16_f16(af1, bfa, acc[1][0], 0, 0, 0); \
        acc[1][1] = __builtin_amdgcn_mfma_f32_32x32x16_f16(af1, bfb, acc[1][1], 0, 0, 0); \
    }

__global__ __launch_bounds__(256, 3) void k_gemm_out() {
    __shared__ f16 As2[2][64 * 68];     // 17.4 KB  [buf][n][m0..63 + pad4], 136-B rows (2-way banks)
    __shared__ float redmax[4], redmin[4];
    int tid = threadIdx.x;
    int lane = tid & 63, wave = tid >> 6;        // 4 waves, each owns a 64-f slice x all 64 n
    int c5 = lane & 31, h5 = lane >> 5;
    int bid = blockIdx.x;                        // 1024 blocks; round-robin -> xcd = bid&7
    int xcd = bid & 7;
    int h = xcd >> 1;
    int ks = xcd & 1;                            // k-slice: m in [ks*2048, +2048)
    int r = bid >> 3;                            // 0..127
    int fh = r & 1;                              // f-half (0..1): 256 f
    int n0 = (r >> 1) * 64;                      // n-tile (0..63)
    int fb = fh * 256;
    int wn = tid >> 2, kq = (tid & 3) * 16;      // weight-gen: row wn (0..63), 16 m's
    const float L2E = 1.44269504f;
    float pv = g_p[h * NN + n0 + wn];
    const float* qh = g_q + h * NN + ks * 2048;
    const f16* Bgl = g_featsH + (size_t)h * FF * NN + (size_t)ks * 2048;
    // ---- in-block M: qmax/qmin over the FULL q row (256 thr x 16) ----
    float mvb;
    {
        const float* qfull = g_q + h * NN + tid * 16;
        float lmax = -1e30f, lmin = 1e30f;
#pragma unroll
        for (int j = 0; j < 4; ++j) {
            f32x4 a = *(const f32x4*)(qfull + j * 4);
#pragma unroll
            for (int k = 0; k < 4; ++k) {
                lmax = fmaxf(lmax, a[k]);
                lmin = fminf(lmin, a[k]);
            }
        }
#pragma unroll
        for (int m = 1; m < 64; m <<= 1) {
            lmax = fmaxf(lmax, __shfl_xor(lmax, m, 64));
            lmin = fminf(lmin, __shfl_xor(lmin, m, 64));
        }
        if (lane == 0) { redmax[wave] = lmax; redmin[wave] = lmin; }
        __syncthreads();
        float qmax = redmax[0], qmin = redmin[0];
#pragma unroll
        for (int w2 = 1; w2 < 4; ++w2) {
            qmax = fmaxf(qmax, redmax[w2]);
            qmin = fminf(qmin, redmin[w2]);
        }
        float se = pv * (pv >= 0.f ? qmax : qmin);
        float Mv = fmaxf(se, 0.3f * se);
        mvb = Mv * L2E + 6.0f;                   // folds the 1/64 overflow guard (2^-6)
    }
    // B-frag row pointers (invariant): jt=0 -> f = fb + wave*64 + c5; jt=1 -> +32
    const f16* rowA = Bgl + (size_t)(fb + wave * 64 + c5) * NN;
    const f16* rowB = rowA + (size_t)32 * NN;
    float zacc = 0.f;
    f32x16 acc[2][2] = {};
    f16x8 wA, wB;                                // pipeline regs: weights for step t+1

    // ---- prologue: w(0) -> As[0]; w(1) -> regs ----
    {
        const float* qp = qh + kq;
        f32x4 q0 = *(const f32x4*)qp, q1 = *(const f32x4*)(qp + 4),
              q2 = *(const f32x4*)(qp + 8), q3 = *(const f32x4*)(qp + 12);
        GEN8(q0, q1, wA);
        GEN8(q2, q3, wB);
        *(f16x8*)&As2[0][wn * 68 + kq] = wA;
        *(f16x8*)&As2[0][wn * 68 + kq + 8] = wB;
        const float* qp1 = qh + 64 + kq;
        q0 = *(const f32x4*)qp1; q1 = *(const f32x4*)(qp1 + 4);
        q2 = *(const f32x4*)(qp1 + 8); q3 = *(const f32x4*)(qp1 + 12);
        GEN8(q0, q1, wA);                        // w(1) held in regs
        GEN8(q2, q3, wB);
    }
    __syncthreads();

    int cur = 0;
    for (int t = 0; t < 32; ++t) {
        int mb = t * 64 + h5 * 8;
        // B frags for sk0/sk1
        f16x8 b00 = *(const f16x8*)(rowA + mb);
        f16x8 b01 = *(const f16x8*)(rowB + mb);
        f16x8 b10 = *(const f16x8*)(rowA + mb + 16);
        f16x8 b11 = *(const f16x8*)(rowB + mb + 16);
        // write w(t+1) into the other buffer (read next step, after the end barrier)
        if (t < 31) {
            int nxt = cur ^ 1;
            *(f16x8*)&As2[nxt][wn * 68 + kq] = wA;
            *(f16x8*)&As2[nxt][wn * 68 + kq + 8] = wB;
        }
        // q for step t+2 (consumed by GEN8s mid-step)
        f32x4 q0, q1, q2, q3;
        if (t < 30) {
            const float* qp = qh + t * 64 + 128 + kq;
            q0 = *(const f32x4*)qp; q1 = *(const f32x4*)(qp + 4);
            q2 = *(const f32x4*)(qp + 8); q3 = *(const f32x4*)(qp + 12);
        }
        SKSTEP(0, b00, b01);
        SKSTEP(1, b10, b11);
        // B frags for sk2/sk3 (reuse register slots)
        f16x8 b20 = *(const f16x8*)(rowA + mb + 32);
        f16x8 b21 = *(const f16x8*)(rowB + mb + 32);
        f16x8 b30 = *(const f16x8*)(rowA + mb + 48);
        f16x8 b31 = *(const f16x8*)(rowB + mb + 48);
        if (t < 30) { GEN8(q0, q1, wA); GEN8(q2, q3, wB); }
        SKSTEP(2, b20, b21);
        SKSTEP(3, b30, b31);
        __syncthreads();   // single barrier: As[nxt] writes visible; As[cur] safe to rewrite
        cur ^= 1;
    }
    // row weight-sum: 4 threads (kq quads) per row -> quad reduce, one writer
    // (both f-half blocks write bit-identical values - benign)
    zacc += __shfl_xor(zacc, 1, 64);
    zacc += __shfl_xor(zacc, 2, 64);
    if ((tid & 3) == 0) g_Zp[(size_t)(h * 2 + ks) * NN + n0 + wn] = zacc;
    f16* O = g_oaccH + (size_t)(h * 2 + ks) * NN * FF;
#pragma unroll
    for (int it = 0; it < 2; ++it)
#pragma unroll
        for (int jt = 0; jt < 2; ++jt) {
            int f = fb + wave * 64 + jt * 32 + c5;
#pragma unroll
            for (int qd = 0; qd < 4; ++qd) {
                int r0 = n0 + it * 32 + qd * 8 + h5 * 4;
#pragma unroll
                for (int rr = 0; rr < 4; ++rr)
                    O[(size_t)(r0 + rr) * FF + f] = (f16)acc[it][jt][qd * 4 + rr];
            }
        }
}

// ---------------- final: out = relu(sum_h (0.25/Z_h[n]) * (slab_h0 + slab_h1)) ----------------
__global__ void k_reduce(float* __restrict__ out) {
    int t = blockIdx.x * 256 + threadIdx.x;   // 1024 blocks; 8 f-elems per thread, one row n
    size_t i = (size_t)t * 8;
    int n = t >> 6;                           // i / 512
    const size_t NF = (size_t)NN * FF;
    float s[8] = {0.f, 0.f, 0.f, 0.f, 0.f, 0.f, 0.f, 0.f};
#pragma unroll
    for (int h = 0; h < HH; ++h) {
        float Z = g_Zp[(size_t)(2 * h) * NN + n] + g_Zp[(size_t)(2 * h + 1) * NN + n];
        float sc = 0.25f / Z;
        f16x8 a = *(const f16x8*)(g_oaccH + (size_t)(2 * h) * NF + i);
        f16x8 bsl = *(const f16x8*)(g_oaccH + (size_t)(2 * h + 1) * NF + i);
#pragma unroll
        for (int rr = 0; rr < 8; ++rr) s[rr] += ((float)a[rr] + (float)bsl[rr]) * sc;
    }
    f32x4 o0, o1;
#pragma unroll
    for (int rr = 0; rr < 4; ++rr) o0[rr] = fmaxf(s[rr], 0.f);
#pragma unroll
    for (int rr = 0; rr < 4; ++rr) o1[rr] = fmaxf(s[4 + rr], 0.f);
    *(f32x4*)(out + i) = o0;
    *(f32x4*)(out + i + 4) = o1;
}

extern "C" void kernel_launch(void* const* d_in, const int* in_sizes, int n_in,
                              void* d_out, int out_size, void* d_ws, size_t ws_size,
                              hipStream_t stream) {
    (void)in_sizes; (void)n_in; (void)out_size; (void)d_ws; (void)ws_size;
    const float* nodes  = (const float*)d_in[0];
    const float* edges  = (const float*)d_in[1];
    const float* labels = (const float*)d_in[2];
    const float* We     = (const float*)d_in[3];
    const float* be     = (const float*)d_in[4];
    const float* W      = (const float*)d_in[5];
    const float* b      = (const float*)d_in[6];
    const float* u      = (const float*)d_in[7];
    const float* v      = (const float*)d_in[8];

    k_prep<<<PREP_CONV + PREP_TRAN + PREP_UV, 256, 0, stream>>>(nodes, edges, labels, We, W, be, b, u, v);
    k_pq<<<4096, 256, 0, stream>>>();
    k_gemm_feats<<<dim3(32, 4, 4), 256, 0, stream>>>();
    k_gemm_out<<<1024, 256, 0, stream>>>();
    k_reduce<<<1024, 256, 0, stream>>>((float*)d_out);
}

// Round 11
// 269.040 us; speedup vs baseline: 1.0352x; 1.0352x over previous
//
#include <hip/hip_runtime.h>

#define NN 4096
#define DD 512
#define FF 512
#define HH 4
#define KK 1024   // concat GEMM depth

typedef _Float16 f16;
typedef f16 f16x8 __attribute__((ext_vector_type(8)));
typedef f16 f16x4 __attribute__((ext_vector_type(4)));
typedef float f32x4 __attribute__((ext_vector_type(4)));
typedef float f32x16 __attribute__((ext_vector_type(16)));

// ---------------- async global->LDS (16 B per lane; LDS dest = uniform base + lane*16) ----------------
typedef __attribute__((address_space(1))) void gvoid;
typedef __attribute__((address_space(3))) void svoid;
__device__ __forceinline__ void glds16(const void* g, void* s) {
    __builtin_amdgcn_global_load_lds((gvoid*)g, (svoid*)s, 16, 0, 0);
}

// ---------------- static device workspace (fully rewritten every call) ----------------
__device__ __attribute__((aligned(16))) f16 g_catA[NN * KK];         //  8 MB  [n][ nodes(512) | X(512) ]
__device__ __attribute__((aligned(16))) f16 g_catB[HH * FF * KK];    //  4 MB  [h][f][ W_h^T(512) | We^T(512) ]
__device__ __attribute__((aligned(16))) f16 g_featsH[HH * FF * NN];  // 16 MB  (feats+e)^T
__device__ __attribute__((aligned(16))) f16 g_oaccH[(size_t)2 * HH * NN * FF]; // 33.5 MB f16 partial slabs
__device__ float g_Zp[2 * HH * NN];                                  // per-(h,ks) row weight-sums
__device__ float g_bcat[HH * FF];                                    // b_h[f] + be[f]
__device__ float g_tu[HH * DD], g_tv[HH * DD], g_bu[HH], g_bv[HH];
__device__ float g_p[HH * NN], g_q[HH * NN];

#define PREP_CONV 4104    // (2*NN*DD/4 + HH*FF) / 256 blocks
#define PREP_TRAN 320
#define PREP_UV   513

// ---------------- fused prep: fp32->f16 concat staging (vectorized) + transposes + u/v proj ----------------
__global__ __launch_bounds__(256) void k_prep(const float* __restrict__ nodes, const float* __restrict__ edges,
                                              const float* __restrict__ labels, const float* __restrict__ We,
                                              const float* __restrict__ W, const float* __restrict__ be,
                                              const float* __restrict__ b, const float* __restrict__ u,
                                              const float* __restrict__ v) {
    __shared__ float lds[64 * 65];
    int bx = blockIdx.x;
    int tid = threadIdx.x;
    if (bx < PREP_CONV) {
        int id = bx * 256 + tid;
        const int NQ = NN * DD / 4;              // 524288 float4 groups
        if (id < NQ) {                           // nodes -> catA[:, 0:512]
            f32x4 vv = *(const f32x4*)(nodes + (size_t)id * 4);
            f16x4 ov;
#pragma unroll
            for (int k = 0; k < 4; ++k) ov[k] = (f16)vv[k];
            *(f16x4*)&g_catA[(size_t)(id >> 7) * KK + (id & 127) * 4] = ov;
            return;
        }
        id -= NQ;
        if (id < NQ) {                           // edges+labels -> catA[:, 512:1024]
            f32x4 ev = *(const f32x4*)(edges  + (size_t)id * 4);
            f32x4 lv = *(const f32x4*)(labels + (size_t)id * 4);
            f16x4 ov;
#pragma unroll
            for (int k = 0; k < 4; ++k) ov[k] = (f16)(ev[k] + lv[k]);
            *(f16x4*)&g_catA[(size_t)(id >> 7) * KK + 512 + (id & 127) * 4] = ov;
            return;
        }
        id -= NQ;
        if (id < HH * FF) { g_bcat[id] = b[id] + be[id & 511]; return; }
        return;
    }
    if (bx < PREP_CONV + PREP_TRAN) {
        int bid = bx - PREP_CONV;                    // 0..319
        int mi = bid >> 6;                           // 0 = We, 1..4 = W head
        int t64 = bid & 63;
        const float* src = (mi == 0) ? We : (W + (size_t)(mi - 1) * DD * FF);
        int ti = t64 >> 3, tj = t64 & 7;             // 64x64 tile coords in [d][f]
        int r = tid >> 2, cseg = (tid & 3) * 16;
#pragma unroll
        for (int kq = 0; kq < 4; ++kq) {
            f32x4 vv = *(const f32x4*)(src + (size_t)(ti * 64 + r) * 512 + tj * 64 + cseg + kq * 4);
            *(f32x4*)&lds[r * 65 + cseg + kq * 4] = vv;
        }
        __syncthreads();
        int fl = tid >> 2, dseg = (tid & 3) * 16;
        f16x8 o0, o1;
#pragma unroll
        for (int k = 0; k < 8; ++k) o0[k] = (f16)lds[(dseg + k) * 65 + fl];
#pragma unroll
        for (int k = 0; k < 8; ++k) o1[k] = (f16)lds[(dseg + 8 + k) * 65 + fl];
        size_t frow = (size_t)(tj * 64 + fl);
        size_t dcol = (size_t)(ti * 64 + dseg);
        if (mi == 0) {                               // We^T -> every head's [512:1024] slice
#pragma unroll
            for (int hh = 0; hh < HH; ++hh) {
                size_t ob = ((size_t)hh * FF + frow) * KK + 512 + dcol;
                *(f16x8*)&g_catB[ob] = o0;
                *(f16x8*)&g_catB[ob + 8] = o1;
            }
        } else {                                     // W_h^T -> head's [0:512] slice
            size_t ob = ((size_t)(mi - 1) * FF + frow) * KK + dcol;
            *(f16x8*)&g_catB[ob] = o0;
            *(f16x8*)&g_catB[ob + 8] = o1;
        }
        return;
    }
    {
        int row = (bx - PREP_CONV - PREP_TRAN) * 4 + (tid >> 6);   // 2052 rows
        int lane = tid & 63;
        float su = 0.f, sv = 0.f;
        if (row < HH * DD) {
            int h = row >> 9, d = row & 511;
            size_t wb = (size_t)h * DD * FF + (size_t)d * FF;
#pragma unroll
            for (int j = 0; j < 8; ++j) {
                int f = lane + 64 * j;
                float wv = W[wb + f];
                su += wv * u[(size_t)h * FF + f];
                sv += wv * v[(size_t)h * FF + f];
            }
        } else if (row < HH * DD + HH) {
            int h = row - HH * DD;
#pragma unroll
            for (int j = 0; j < 8; ++j) {
                int f = lane + 64 * j;
                float bvv = b[(size_t)h * FF + f];
                su += bvv * u[(size_t)h * FF + f];
                sv += bvv * v[(size_t)h * FF + f];
            }
        }
#pragma unroll
        for (int m = 1; m < 64; m <<= 1) {
            su += __shfl_xor(su, m, 64);
            sv += __shfl_xor(sv, m, 64);
        }
        if (lane == 0 && row < HH * DD + HH) {
            if (row < HH * DD) { g_tu[row] = su; g_tv[row] = sv; }
            else { g_bu[row - HH * DD] = su; g_bv[row - HH * DD] = sv; }
        }
    }
}

// ---------------- p[h][n] = nodes[n].t_u[h] + bu[h];  q likewise (vectorized loads) ----------------
__global__ __launch_bounds__(256) void k_pq() {
    int row = blockIdx.x * 4 + (threadIdx.x >> 6);    // 4096 blocks -> 16384 rows = H*N
    int lane = threadIdx.x & 63;
    int h = row >> 12, n = row & 4095;
    const f16* nb = g_catA + (size_t)n * KK + lane * 8;   // nodes slice, 8 contiguous d's per lane
    const float* tu = g_tu + h * DD + lane * 8;
    const float* tv = g_tv + h * DD + lane * 8;
    f16x8 nv8 = *(const f16x8*)nb;
    f32x4 tu0 = *(const f32x4*)tu, tu1 = *(const f32x4*)(tu + 4);
    f32x4 tv0 = *(const f32x4*)tv, tv1 = *(const f32x4*)(tv + 4);
    float pa = 0.f, qa = 0.f;
#pragma unroll
    for (int j = 0; j < 4; ++j) {
        float nv = (float)nv8[j];
        pa += nv * tu0[j];
        qa += nv * tv0[j];
    }
#pragma unroll
    for (int j = 0; j < 4; ++j) {
        float nv = (float)nv8[4 + j];
        pa += nv * tu1[j];
        qa += nv * tv1[j];
    }
#pragma unroll
    for (int m = 1; m < 64; m <<= 1) {
        pa += __shfl_xor(pa, m, 64);
        qa += __shfl_xor(qa, m, 64);
    }
    if (lane == 0) {
        g_p[row] = pa + g_bu[h];
        g_q[row] = qa + g_bv[h];
    }
}

// ---------------- concat GEMM v3 (BK=128, 8 intervals): featsH[h][f][n] = f16(catA@catB^T + bcat)
//                  tile 128n x 128f, all-glds staging, 16-chunk XOR swizzle ----------------
__global__ __launch_bounds__(256, 2) void k_gemm_feats() {
    __shared__ f16 As[128 * 128];       // 32 KB  [n][k0..127], 256-B rows, chunk-swizzled
    __shared__ f16 Bs[128 * 128];       // 32 KB  [f][k0..127]
    int tid = threadIdx.x;
    int lane = tid & 63, wave = tid >> 6;        // 4 waves
    int wr = wave & 1, wc = wave >> 1;
    int c = lane & 15, g = lane >> 4;
    int n0 = blockIdx.x * 128, f0 = blockIdx.y * 128;
    int h = blockIdx.z;
    const f16* Bgl = g_catB + (size_t)h * FF * KK;
    int r4 = lane >> 4;                  // row within 4-row glds group (0..3)
    int ch = lane & 15;                  // chunk slot this lane fills (16 chunks of 16B per row)
    f32x4 acc[4][4] = {};
    for (int kk = 0; kk < KK; kk += 128) {
        __syncthreads();
#pragma unroll
        for (int j = 0; j < 8; ++j) {
            int rowb = wave * 32 + j * 4;        // wave stages rows [wave*32, wave*32+32)
            int row = rowb + r4;
            int src = (ch ^ (row & 15)) * 8;     // swizzled source k-chunk (f16 elems)
            glds16(g_catA + (size_t)(n0 + row) * KK + kk + src, &As[rowb * 128]);
            glds16(Bgl    + (size_t)(f0 + row) * KK + kk + src, &Bs[rowb * 128]);
        }
        __syncthreads();
#pragma unroll
        for (int s = 0; s < 4; ++s) {
            f16x8 af[4], bf[4];
#pragma unroll
            for (int i = 0; i < 4; ++i) {
                int ra = wr * 64 + i * 16 + c;
                af[i] = *(const f16x8*)&As[ra * 128 + (((s * 4 + g) ^ (ra & 15)) * 8)];
            }
#pragma unroll
            for (int jj = 0; jj < 4; ++jj) {
                int rb = wc * 64 + jj * 16 + c;
                bf[jj] = *(const f16x8*)&Bs[rb * 128 + (((s * 4 + g) ^ (rb & 15)) * 8)];
            }
#pragma unroll
            for (int i = 0; i < 4; ++i)
#pragma unroll
                for (int jj = 0; jj < 4; ++jj)
                    acc[i][jj] = __builtin_amdgcn_mfma_f32_16x16x32_f16(af[i], bf[jj], acc[i][jj], 0, 0, 0);
        }
    }
#pragma unroll
    for (int jj = 0; jj < 4; ++jj) {
        int f = f0 + wc * 64 + jj * 16 + c;
        float bv = g_bcat[h * FF + f];
#pragma unroll
        for (int i = 0; i < 4; ++i) {
            int r0 = n0 + wr * 64 + i * 16 + g * 4;
            f16x4 ov;
#pragma unroll
            for (int rr = 0; rr < 4; ++rr) ov[rr] = (f16)(acc[i][jj][rr] + bv);
            *(f16x4*)(g_featsH + ((size_t)h * FF + f) * NN + r0) = ov;
        }
    }
}

// ---------------- GEMM3 v10: occupancy WITHOUT duplication. 512-thr/8-wave blocks spanning
//                  full f=512 (weights generated exactly once), tile 64n x 512f, acc[2][2]=64 AGPR,
//                  launch_bounds(512,4) -> 2 blocks/CU = 2 independent barrier domains per SIMD
//                  (4 waves/SIMD). Keeps: B direct-from-L2 (XCD-pinned), pad-68 As (0 conflicts),
//                  in-block M, single barrier/step, setprio around MFMA clusters. ----------------
#define WCALC(qv, dstvec, idx)                                              \
    {                                                                       \
        float s_ = pv * (qv);                                               \
        s_ = fmaxf(s_, 0.3f * s_);                                          \
        float e_ = __builtin_amdgcn_exp2f(__builtin_fmaf(s_, L2E, -mvb));   \
        zacc += e_;                                                         \
        dstvec[idx] = (f16)e_;                                              \
    }
#define GEN8(qa, qb, w)                                                     \
    {                                                                       \
        _Pragma("unroll") for (int k_ = 0; k_ < 4; ++k_) {                  \
            WCALC((qa)[k_], w, k_);                                         \
            WCALC((qb)[k_], w, 4 + k_);                                     \
        }                                                                   \
    }
// one sub-k: 2 af ds_reads + 4 MFMA against a B-frag pair
#define SKSTEP(skidx, bfa, bfb)                                             \
    {                                                                       \
        int cA_ = ((skidx) * 2 + h5) * 8;                                   \
        f16x8 af0 = *(const f16x8*)&As2[cur][(c5) * 68 + cA_];              \
        f16x8 af1 = *(const f16x8*)&As2[cur][(32 + c5) * 68 + cA_];         \
        __builtin_amdgcn_s_setprio(1);                                      \
        acc[0][0] = __builtin_amdgcn_mfma_f32_32x32x16_f16(af0, bfa, acc[0][0], 0, 0, 0); \
        acc[0][1] = __builtin_amdgcn_mfma_f32_32x32x16_f16(af0, bfb, acc[0][1], 0, 0, 0); \
        acc[1][0] = __builtin_amdgcn_mfma_f32_32x32x16_f16(af1, bfa, acc[1][0], 0, 0, 0); \
        acc[1][1] = __builtin_amdgcn_mfma_f32_32x32x16_f16(af1, bfb, acc[1][1], 0, 0, 0); \
        __builtin_amdgcn_s_setprio(0);                                      \
    }

__global__ __launch_bounds__(512, 4) void k_gemm_out() {
    __shared__ f16 As2[2][64 * 68];     // 17.4 KB  [buf][n][m0..63 + pad4], 136-B rows (2-way banks)
    __shared__ float redmax[8], redmin[8];
    int tid = threadIdx.x;
    int lane = tid & 63, wave = tid >> 6;        // 8 waves, each owns a 64-f slice x all 64 n
    int c5 = lane & 31, h5 = lane >> 5;
    int bid = blockIdx.x;                        // 512 blocks: xcd = bid&7 -> (h,ks); n-tiles within
    int xcd = bid & 7;
    int h = xcd >> 1;
    int ks = xcd & 1;                            // k-slice: m in [ks*2048, +2048)
    int n0 = (bid >> 3) * 64;                    // n-tile (0..63)
    int wn = tid >> 3, kq = (tid & 7) * 8;       // weight-gen: row wn (0..63), 8 m's per thread
    const float L2E = 1.44269504f;
    float pv = g_p[h * NN + n0 + wn];
    const float* qh = g_q + h * NN + ks * 2048;
    const f16* Bgl = g_featsH + (size_t)h * FF * NN + (size_t)ks * 2048;
    // ---- in-block M: qmax/qmin over the FULL q row (512 thr x 8) ----
    float mvb;
    {
        const float* qfull = g_q + h * NN + tid * 8;
        f32x4 a = *(const f32x4*)qfull, b2 = *(const f32x4*)(qfull + 4);
        float lmax = -1e30f, lmin = 1e30f;
#pragma unroll
        for (int j = 0; j < 4; ++j) {
            lmax = fmaxf(lmax, fmaxf(a[j], b2[j]));
            lmin = fminf(lmin, fminf(a[j], b2[j]));
        }
#pragma unroll
        for (int m = 1; m < 64; m <<= 1) {
            lmax = fmaxf(lmax, __shfl_xor(lmax, m, 64));
            lmin = fminf(lmin, __shfl_xor(lmin, m, 64));
        }
        if (lane == 0) { redmax[wave] = lmax; redmin[wave] = lmin; }
        __syncthreads();
        float qmax = redmax[0], qmin = redmin[0];
#pragma unroll
        for (int w2 = 1; w2 < 8; ++w2) {
            qmax = fmaxf(qmax, redmax[w2]);
            qmin = fminf(qmin, redmin[w2]);
        }
        float se = pv * (pv >= 0.f ? qmax : qmin);
        float Mv = fmaxf(se, 0.3f * se);
        mvb = Mv * L2E + 6.0f;                   // folds the 1/64 overflow guard (2^-6)
    }
    // B-frag row pointers (invariant): wave's f-slice = [wave*64, wave*64+64)
    const f16* rowA = Bgl + (size_t)(wave * 64 + c5) * NN;
    const f16* rowB = rowA + (size_t)32 * NN;
    float zacc = 0.f;
    f32x16 acc[2][2] = {};
    f16x8 wA;                                    // pipeline reg: weights for step t+1

    // ---- prologue: w(0) -> As[0]; w(1) -> regs ----
    {
        const float* qp = qh + kq;
        f32x4 q0 = *(const f32x4*)qp, q1 = *(const f32x4*)(qp + 4);
        GEN8(q0, q1, wA);
        *(f16x8*)&As2[0][wn * 68 + kq] = wA;
        const float* qp1 = qh + 64 + kq;
        q0 = *(const f32x4*)qp1; q1 = *(const f32x4*)(qp1 + 4);
        GEN8(q0, q1, wA);                        // w(1) held in regs
    }
    __syncthreads();

    int cur = 0;
    for (int t = 0; t < 32; ++t) {
        int mb = t * 64 + h5 * 8;
        // B frags for sk0/sk1
        f16x8 b00 = *(const f16x8*)(rowA + mb);
        f16x8 b01 = *(const f16x8*)(rowB + mb);
        f16x8 b10 = *(const f16x8*)(rowA + mb + 16);
        f16x8 b11 = *(const f16x8*)(rowB + mb + 16);
        // write w(t+1) into the other buffer (read next step, after the end barrier)
        if (t < 31) {
            int nxt = cur ^ 1;
            *(f16x8*)&As2[nxt][wn * 68 + kq] = wA;
        }
        // q for step t+2 (consumed by GEN8 mid-step)
        f32x4 q0, q1;
        if (t < 30) {
            const float* qp = qh + t * 64 + 128 + kq;
            q0 = *(const f32x4*)qp; q1 = *(const f32x4*)(qp + 4);
        }
        SKSTEP(0, b00, b01);
        SKSTEP(1, b10, b11);
        // B frags for sk2/sk3 (reuse register slots)
        f16x8 b20 = *(const f16x8*)(rowA + mb + 32);
        f16x8 b21 = *(const f16x8*)(rowB + mb + 32);
        f16x8 b30 = *(const f16x8*)(rowA + mb + 48);
        f16x8 b31 = *(const f16x8*)(rowB + mb + 48);
        if (t < 30) { GEN8(q0, q1, wA); }        // weight-gen for t+2 (once, no duplication)
        SKSTEP(2, b20, b21);
        SKSTEP(3, b30, b31);
        __syncthreads();   // single barrier: As[nxt] writes visible; As[cur] safe to rewrite
        cur ^= 1;
    }
    // row weight-sum: 8 threads (kq octets) per row -> reduce, one writer
    zacc += __shfl_xor(zacc, 1, 64);
    zacc += __shfl_xor(zacc, 2, 64);
    zacc += __shfl_xor(zacc, 4, 64);
    if ((tid & 7) == 0) g_Zp[(size_t)(h * 2 + ks) * NN + n0 + wn] = zacc;
    f16* O = g_oaccH + (size_t)(h * 2 + ks) * NN * FF;
#pragma unroll
    for (int it = 0; it < 2; ++it)
#pragma unroll
        for (int jt = 0; jt < 2; ++jt) {
            int f = wave * 64 + jt * 32 + c5;
#pragma unroll
            for (int qd = 0; qd < 4; ++qd) {
                int r0 = n0 + it * 32 + qd * 8 + h5 * 4;
#pragma unroll
                for (int rr = 0; rr < 4; ++rr)
                    O[(size_t)(r0 + rr) * FF + f] = (f16)acc[it][jt][qd * 4 + rr];
            }
        }
}

// ---------------- final: out = relu(sum_h (0.25/Z_h[n]) * (slab_h0 + slab_h1)) ----------------
__global__ void k_reduce(float* __restrict__ out) {
    int t = blockIdx.x * 256 + threadIdx.x;   // 1024 blocks; 8 f-elems per thread, one row n
    size_t i = (size_t)t * 8;
    int n = t >> 6;                           // i / 512
    const size_t NF = (size_t)NN * FF;
    float s[8] = {0.f, 0.f, 0.f, 0.f, 0.f, 0.f, 0.f, 0.f};
#pragma unroll
    for (int h = 0; h < HH; ++h) {
        float Z = g_Zp[(size_t)(2 * h) * NN + n] + g_Zp[(size_t)(2 * h + 1) * NN + n];
        float sc = 0.25f / Z;
        f16x8 a = *(const f16x8*)(g_oaccH + (size_t)(2 * h) * NF + i);
        f16x8 bsl = *(const f16x8*)(g_oaccH + (size_t)(2 * h + 1) * NF + i);
#pragma unroll
        for (int rr = 0; rr < 8; ++rr) s[rr] += ((float)a[rr] + (float)bsl[rr]) * sc;
    }
    f32x4 o0, o1;
#pragma unroll
    for (int rr = 0; rr < 4; ++rr) o0[rr] = fmaxf(s[rr], 0.f);
#pragma unroll
    for (int rr = 0; rr < 4; ++rr) o1[rr] = fmaxf(s[4 + rr], 0.f);
    *(f32x4*)(out + i) = o0;
    *(f32x4*)(out + i + 4) = o1;
}

extern "C" void kernel_launch(void* const* d_in, const int* in_sizes, int n_in,
                              void* d_out, int out_size, void* d_ws, size_t ws_size,
                              hipStream_t stream) {
    (void)in_sizes; (void)n_in; (void)out_size; (void)d_ws; (void)ws_size;
    const float* nodes  = (const float*)d_in[0];
    const float* edges  = (const float*)d_in[1];
    const float* labels = (const float*)d_in[2];
    const float* We     = (const float*)d_in[3];
    const float* be     = (const float*)d_in[4];
    const float* W      = (const float*)d_in[5];
    const float* b      = (const float*)d_in[6];
    const float* u      = (const float*)d_in[7];
    const float* v      = (const float*)d_in[8];

    k_prep<<<PREP_CONV + PREP_TRAN + PREP_UV, 256, 0, stream>>>(nodes, edges, labels, We, W, be, b, u, v);
    k_pq<<<4096, 256, 0, stream>>>();
    k_gemm_feats<<<dim3(32, 4, 4), 256, 0, stream>>>();
    k_gemm_out<<<512, 512, 0, stream>>>();
    k_reduce<<<1024, 256, 0, stream>>>((float*)d_out);
}

// Round 12
// 216.596 us; speedup vs baseline: 1.2859x; 1.2421x over previous
//
#include <hip/hip_runtime.h>

#define NN 4096
#define DD 512
#define FF 512
#define HH 4
#define KK 1024   // concat GEMM depth

typedef _Float16 f16;
typedef f16 f16x8 __attribute__((ext_vector_type(8)));
typedef f16 f16x4 __attribute__((ext_vector_type(4)));
typedef float f32x4 __attribute__((ext_vector_type(4)));
typedef float f32x16 __attribute__((ext_vector_type(16)));

// ---------------- async global->LDS (16 B per lane; LDS dest = uniform base + lane*16) ----------------
typedef __attribute__((address_space(1))) void gvoid;
typedef __attribute__((address_space(3))) void svoid;
__device__ __forceinline__ void glds16(const void* g, void* s) {
    __builtin_amdgcn_global_load_lds((gvoid*)g, (svoid*)s, 16, 0, 0);
}

// ---------------- static device workspace (fully rewritten every call) ----------------
__device__ __attribute__((aligned(16))) f16 g_catA[NN * KK];         //  8 MB  [n][ nodes(512) | X(512) ]
__device__ __attribute__((aligned(16))) f16 g_catB[HH * FF * KK];    //  4 MB  [h][f][ W_h^T(512) | We^T(512) ]
__device__ __attribute__((aligned(16))) f16 g_featsH[HH * FF * NN];  // 16 MB  (feats+e)^T
__device__ __attribute__((aligned(16))) f16 g_oaccH[(size_t)2 * HH * NN * FF]; // 33.5 MB f16 partial slabs
__device__ float g_Zp[2 * HH * NN];                                  // per-(h,ks) row weight-sums
__device__ float g_bcat[HH * FF];                                    // b_h[f] + be[f]
__device__ float g_tu[HH * DD], g_tv[HH * DD], g_bu[HH], g_bv[HH];
__device__ float g_p[HH * NN], g_q[HH * NN];

#define PREP_CONV 4104    // (2*NN*DD/4 + HH*FF) / 256 blocks
#define PREP_TRAN 320
#define PREP_UV   513

// ---------------- fused prep: fp32->f16 concat staging (vectorized) + transposes + u/v proj ----------------
__global__ __launch_bounds__(256) void k_prep(const float* __restrict__ nodes, const float* __restrict__ edges,
                                              const float* __restrict__ labels, const float* __restrict__ We,
                                              const float* __restrict__ W, const float* __restrict__ be,
                                              const float* __restrict__ b, const float* __restrict__ u,
                                              const float* __restrict__ v) {
    __shared__ float lds[64 * 65];
    int bx = blockIdx.x;
    int tid = threadIdx.x;
    if (bx < PREP_CONV) {
        int id = bx * 256 + tid;
        const int NQ = NN * DD / 4;              // 524288 float4 groups
        if (id < NQ) {                           // nodes -> catA[:, 0:512]
            f32x4 vv = *(const f32x4*)(nodes + (size_t)id * 4);
            f16x4 ov;
#pragma unroll
            for (int k = 0; k < 4; ++k) ov[k] = (f16)vv[k];
            *(f16x4*)&g_catA[(size_t)(id >> 7) * KK + (id & 127) * 4] = ov;
            return;
        }
        id -= NQ;
        if (id < NQ) {                           // edges+labels -> catA[:, 512:1024]
            f32x4 ev = *(const f32x4*)(edges  + (size_t)id * 4);
            f32x4 lv = *(const f32x4*)(labels + (size_t)id * 4);
            f16x4 ov;
#pragma unroll
            for (int k = 0; k < 4; ++k) ov[k] = (f16)(ev[k] + lv[k]);
            *(f16x4*)&g_catA[(size_t)(id >> 7) * KK + 512 + (id & 127) * 4] = ov;
            return;
        }
        id -= NQ;
        if (id < HH * FF) { g_bcat[id] = b[id] + be[id & 511]; return; }
        return;
    }
    if (bx < PREP_CONV + PREP_TRAN) {
        int bid = bx - PREP_CONV;                    // 0..319
        int mi = bid >> 6;                           // 0 = We, 1..4 = W head
        int t64 = bid & 63;
        const float* src = (mi == 0) ? We : (W + (size_t)(mi - 1) * DD * FF);
        int ti = t64 >> 3, tj = t64 & 7;             // 64x64 tile coords in [d][f]
        int r = tid >> 2, cseg = (tid & 3) * 16;
#pragma unroll
        for (int kq = 0; kq < 4; ++kq) {
            f32x4 vv = *(const f32x4*)(src + (size_t)(ti * 64 + r) * 512 + tj * 64 + cseg + kq * 4);
            *(f32x4*)&lds[r * 65 + cseg + kq * 4] = vv;
        }
        __syncthreads();
        int fl = tid >> 2, dseg = (tid & 3) * 16;
        f16x8 o0, o1;
#pragma unroll
        for (int k = 0; k < 8; ++k) o0[k] = (f16)lds[(dseg + k) * 65 + fl];
#pragma unroll
        for (int k = 0; k < 8; ++k) o1[k] = (f16)lds[(dseg + 8 + k) * 65 + fl];
        size_t frow = (size_t)(tj * 64 + fl);
        size_t dcol = (size_t)(ti * 64 + dseg);
        if (mi == 0) {                               // We^T -> every head's [512:1024] slice
#pragma unroll
            for (int hh = 0; hh < HH; ++hh) {
                size_t ob = ((size_t)hh * FF + frow) * KK + 512 + dcol;
                *(f16x8*)&g_catB[ob] = o0;
                *(f16x8*)&g_catB[ob + 8] = o1;
            }
        } else {                                     // W_h^T -> head's [0:512] slice
            size_t ob = ((size_t)(mi - 1) * FF + frow) * KK + dcol;
            *(f16x8*)&g_catB[ob] = o0;
            *(f16x8*)&g_catB[ob + 8] = o1;
        }
        return;
    }
    {
        int row = (bx - PREP_CONV - PREP_TRAN) * 4 + (tid >> 6);   // 2052 rows
        int lane = tid & 63;
        float su = 0.f, sv = 0.f;
        if (row < HH * DD) {
            int h = row >> 9, d = row & 511;
            size_t wb = (size_t)h * DD * FF + (size_t)d * FF;
#pragma unroll
            for (int j = 0; j < 8; ++j) {
                int f = lane + 64 * j;
                float wv = W[wb + f];
                su += wv * u[(size_t)h * FF + f];
                sv += wv * v[(size_t)h * FF + f];
            }
        } else if (row < HH * DD + HH) {
            int h = row - HH * DD;
#pragma unroll
            for (int j = 0; j < 8; ++j) {
                int f = lane + 64 * j;
                float bvv = b[(size_t)h * FF + f];
                su += bvv * u[(size_t)h * FF + f];
                sv += bvv * v[(size_t)h * FF + f];
            }
        }
#pragma unroll
        for (int m = 1; m < 64; m <<= 1) {
            su += __shfl_xor(su, m, 64);
            sv += __shfl_xor(sv, m, 64);
        }
        if (lane == 0 && row < HH * DD + HH) {
            if (row < HH * DD) { g_tu[row] = su; g_tv[row] = sv; }
            else { g_bu[row - HH * DD] = su; g_bv[row - HH * DD] = sv; }
        }
    }
}

// ---------------- p[h][n] = nodes[n].t_u[h] + bu[h];  q likewise (vectorized loads) ----------------
__global__ __launch_bounds__(256) void k_pq() {
    int row = blockIdx.x * 4 + (threadIdx.x >> 6);    // 4096 blocks -> 16384 rows = H*N
    int lane = threadIdx.x & 63;
    int h = row >> 12, n = row & 4095;
    const f16* nb = g_catA + (size_t)n * KK + lane * 8;   // nodes slice, 8 contiguous d's per lane
    const float* tu = g_tu + h * DD + lane * 8;
    const float* tv = g_tv + h * DD + lane * 8;
    f16x8 nv8 = *(const f16x8*)nb;
    f32x4 tu0 = *(const f32x4*)tu, tu1 = *(const f32x4*)(tu + 4);
    f32x4 tv0 = *(const f32x4*)tv, tv1 = *(const f32x4*)(tv + 4);
    float pa = 0.f, qa = 0.f;
#pragma unroll
    for (int j = 0; j < 4; ++j) {
        float nv = (float)nv8[j];
        pa += nv * tu0[j];
        qa += nv * tv0[j];
    }
#pragma unroll
    for (int j = 0; j < 4; ++j) {
        float nv = (float)nv8[4 + j];
        pa += nv * tu1[j];
        qa += nv * tv1[j];
    }
#pragma unroll
    for (int m = 1; m < 64; m <<= 1) {
        pa += __shfl_xor(pa, m, 64);
        qa += __shfl_xor(qa, m, 64);
    }
    if (lane == 0) {
        g_p[row] = pa + g_bu[h];
        g_q[row] = qa + g_bv[h];
    }
}

// ---------------- concat GEMM v4: 32x32x16 MFMA inner loop (was 16x16x32).
//                  tile 128n x 128f, BK=128, all-glds staging, 16-chunk XOR swizzle (unchanged).
//                  8 sub-k of {4 ds_read_b128 + 4 MFMA}; acc f32x16[2][2]. ----------------
__global__ __launch_bounds__(256, 2) void k_gemm_feats() {
    __shared__ f16 As[128 * 128];       // 32 KB  [n][k0..127], 256-B rows, chunk-swizzled
    __shared__ f16 Bs[128 * 128];       // 32 KB  [f][k0..127]
    int tid = threadIdx.x;
    int lane = tid & 63, wave = tid >> 6;        // 4 waves
    int wr = wave & 1, wc = wave >> 1;
    int c5 = lane & 31, h5 = lane >> 5;
    int n0 = blockIdx.x * 128, f0 = blockIdx.y * 128;
    int h = blockIdx.z;
    const f16* Bgl = g_catB + (size_t)h * FF * KK;
    int r4 = lane >> 4;                  // row within 4-row glds group (0..3)
    int ch = lane & 15;                  // chunk slot this lane fills (16 chunks of 16B per row)
    f32x16 acc[2][2] = {};
    int ra0 = wr * 64 + c5, ra1 = ra0 + 32;
    int rb0 = wc * 64 + c5, rb1 = rb0 + 32;
    for (int kk = 0; kk < KK; kk += 128) {
        __syncthreads();
#pragma unroll
        for (int j = 0; j < 8; ++j) {
            int rowb = wave * 32 + j * 4;        // wave stages rows [wave*32, wave*32+32)
            int row = rowb + r4;
            int src = (ch ^ (row & 15)) * 8;     // swizzled source k-chunk (f16 elems)
            glds16(g_catA + (size_t)(n0 + row) * KK + kk + src, &As[rowb * 128]);
            glds16(Bgl    + (size_t)(f0 + row) * KK + kk + src, &Bs[rowb * 128]);
        }
        __syncthreads();
#pragma unroll
        for (int sk = 0; sk < 8; ++sk) {
            int lc = sk * 2 + h5;                // logical 8-f16 chunk (k = lc*8 .. lc*8+7)
            f16x8 af0 = *(const f16x8*)&As[ra0 * 128 + ((lc ^ (ra0 & 15)) * 8)];
            f16x8 af1 = *(const f16x8*)&As[ra1 * 128 + ((lc ^ (ra1 & 15)) * 8)];
            f16x8 bf0 = *(const f16x8*)&Bs[rb0 * 128 + ((lc ^ (rb0 & 15)) * 8)];
            f16x8 bf1 = *(const f16x8*)&Bs[rb1 * 128 + ((lc ^ (rb1 & 15)) * 8)];
            acc[0][0] = __builtin_amdgcn_mfma_f32_32x32x16_f16(af0, bf0, acc[0][0], 0, 0, 0);
            acc[0][1] = __builtin_amdgcn_mfma_f32_32x32x16_f16(af0, bf1, acc[0][1], 0, 0, 0);
            acc[1][0] = __builtin_amdgcn_mfma_f32_32x32x16_f16(af1, bf0, acc[1][0], 0, 0, 0);
            acc[1][1] = __builtin_amdgcn_mfma_f32_32x32x16_f16(af1, bf1, acc[1][1], 0, 0, 0);
        }
    }
    // C-write: 32x32 C/D mapping col=lane&31, row=(reg&3)+8*(reg>>2)+4*h5 -> featsH[f][n] f16x4 stores
#pragma unroll
    for (int it = 0; it < 2; ++it)
#pragma unroll
        for (int jt = 0; jt < 2; ++jt) {
            int f = f0 + wc * 64 + jt * 32 + c5;
            float bv = g_bcat[h * FF + f];
#pragma unroll
            for (int qd = 0; qd < 4; ++qd) {
                int r0 = n0 + wr * 64 + it * 32 + qd * 8 + h5 * 4;
                f16x4 ov;
#pragma unroll
                for (int rr = 0; rr < 4; ++rr) ov[rr] = (f16)(acc[it][jt][qd * 4 + rr] + bv);
                *(f16x4*)(g_featsH + ((size_t)h * FF + f) * NN + r0) = ov;
            }
        }
}

// ---------------- GEMM3 v11: exact v4 structure (98.4 us proven) + in-block M (k_mstat removed).
//                  32x32x16 MFMA, 4 sub-k steps of {6 ds_read + 8 MFMA},
//                  unified Bs[512][64] (128-B rows, 8-chunk XOR swizzle), dbuf:
//                  stage(t+1) first, one syncthreads per step, GEN8s slotted between sk groups. --------
#define WCALC(qv, dstvec, idx)                                              \
    {                                                                       \
        float s_ = pv * (qv);                                               \
        s_ = fmaxf(s_, 0.3f * s_);                                          \
        float e_ = __builtin_amdgcn_exp2f(__builtin_fmaf(s_, L2E, -mvb));   \
        zacc += e_;                                                         \
        dstvec[idx] = (f16)e_;                                              \
    }
#define GEN8(qa, qb, w)                                                     \
    {                                                                       \
        _Pragma("unroll") for (int k_ = 0; k_ < 4; ++k_) {                  \
            WCALC((qa)[k_], w, k_);                                         \
            WCALC((qb)[k_], w, 4 + k_);                                     \
        }                                                                   \
    }
// stage one 512x64 B-tile: 8 glds16 per lane; lane = r8*8+ch fills row r8, phys chunk ch
#define STAGE_B(buf, kkoff)                                                 \
    {                                                                       \
        _Pragma("unroll") for (int j = 0; j < 8; ++j) {                     \
            int row_ = wave * 64 + j * 8 + r8;                              \
            glds16(Bgl + (size_t)row_ * NN + (kkoff) + ((ch ^ (row_ & 7)) * 8), \
                   &Bs[buf][(wave * 64 + j * 8) * 64]);                     \
        }                                                                   \
    }

__global__ __launch_bounds__(512, 2) void k_gemm_out() {
    __shared__ f16 As2[2][128 * 64];    // 32 KB  [buf][n][k0..63], 128-B rows, chunk^row XOR swizzle
    __shared__ f16 Bs[2][512 * 64];     // 128 KB [buf][f][m0..63], 128-B rows, chunk^row XOR swizzle
    int tid = threadIdx.x;
    int lane = tid & 63, wave = tid >> 6;        // 8 waves
    int wr = wave & 1;                           // n half (0..1)
    int wf = wave >> 1;                          // f quarter (0..3), 128 f each
    int c5 = lane & 31, h5 = lane >> 5;
    int n0 = blockIdx.x * 128;
    int h = blockIdx.y;
    int ks = blockIdx.z;                         // k-slice: m in [ks*2048, +2048)
    int wn = tid >> 2, kq = (tid & 3) * 16;      // weight-gen: row wn (0..127), 16 k's
    const float L2E = 1.44269504f;
    float pv = g_p[h * NN + n0 + wn];
    const float* qh = g_q + h * NN + ks * 2048;
    const f16* Bgl = g_featsH + (size_t)h * FF * NN + (size_t)ks * 2048;
    int r8 = lane >> 3, ch = lane & 7;           // B staging decomposition
    // ---- in-block M: qmax/qmin over the FULL q row (512 thr x 8); scratch = As2 bytes ----
    float mvb;
    {
        const float* qfull = g_q + h * NN + tid * 8;
        f32x4 a = *(const f32x4*)qfull, b2 = *(const f32x4*)(qfull + 4);
        float lmax = -1e30f, lmin = 1e30f;
#pragma unroll
        for (int j = 0; j < 4; ++j) {
            lmax = fmaxf(lmax, fmaxf(a[j], b2[j]));
            lmin = fminf(lmin, fminf(a[j], b2[j]));
        }
#pragma unroll
        for (int m = 1; m < 64; m <<= 1) {
            lmax = fmaxf(lmax, __shfl_xor(lmax, m, 64));
            lmin = fminf(lmin, __shfl_xor(lmin, m, 64));
        }
        float* red = (float*)&As2[0][0];
        if (lane == 0) { red[wave] = lmax; red[8 + wave] = lmin; }
        __syncthreads();
        float qmax = red[0], qmin = red[8];
#pragma unroll
        for (int w2 = 1; w2 < 8; ++w2) {
            qmax = fmaxf(qmax, red[w2]);
            qmin = fminf(qmin, red[8 + w2]);
        }
        float se = pv * (pv >= 0.f ? qmax : qmin);
        float Mv = fmaxf(se, 0.3f * se);
        mvb = Mv * L2E + 6.0f;                   // folds the 1/64 overflow guard (2^-6)
        __syncthreads();                         // red reads done before As2[0] is overwritten
    }
    // As write slots (chunk XOR row&7 swizzle; w0 -> logical chunk 2*(tid&3), w1 -> +1)
    int aw0 = wn * 64 + (((tid & 3) * 2 + 0) ^ (wn & 7)) * 8;
    int aw1 = wn * 64 + (((tid & 3) * 2 + 1) ^ (wn & 7)) * 8;
    // fragment-read row bases (f16 elems); chunk offset computed per sk
    int arow = (wr * 64 + c5) * 64;              // A rows wr*64 + it*32 + c5
    int brow = (wf * 128 + c5) * 64;             // B rows wf*128 + jt*32 + c5
    int csw = (c5 & 7);                          // row-XOR key (same for A and B reads)
    float zacc = 0.f;
    f32x16 acc[2][4] = {};
    f16x8 wA, wB;                                // pipeline regs: weights for step t+1

    // ---- prologue: stage step 0, pre-gen step 1 ----
    {
        const float* qp = qh + kq;
        f32x4 q0 = *(const f32x4*)qp, q1 = *(const f32x4*)(qp + 4),
              q2 = *(const f32x4*)(qp + 8), q3 = *(const f32x4*)(qp + 12);
        GEN8(q0, q1, wA);                        // w(0) k 0..7 of window
        GEN8(q2, q3, wB);
        *(f16x8*)&As2[0][aw0] = wA;
        *(f16x8*)&As2[0][aw1] = wB;
        STAGE_B(0, 0);
        const float* qp1 = qh + 64 + kq;
        q0 = *(const f32x4*)qp1; q1 = *(const f32x4*)(qp1 + 4);
        q2 = *(const f32x4*)(qp1 + 8); q3 = *(const f32x4*)(qp1 + 12);
        GEN8(q0, q1, wA);                        // w(1) held in regs
        GEN8(q2, q3, wB);
    }
    __syncthreads();

    int cur = 0;
    for (int t = 0; t < 32; ++t) {
        // prefetch q for step t+2 (consumed by GEN8s mid-step)
        f32x4 q0, q1, q2, q3;
        if (t < 30) {
            const float* qp = qh + t * 64 + 128 + kq;
            q0 = *(const f32x4*)qp; q1 = *(const f32x4*)(qp + 4);
            q2 = *(const f32x4*)(qp + 8); q3 = *(const f32x4*)(qp + 12);
        }
        // stage step t+1 into the other buffer (loads stay in flight across the whole step)
        if (t < 31) {
            int nxt = cur ^ 1;
            int kk2 = t * 64 + 64;
            STAGE_B(nxt, kk2);
            *(f16x8*)&As2[nxt][aw0] = wA;
            *(f16x8*)&As2[nxt][aw1] = wB;
        }
        // ---- 4 sub-k steps: {2 af + 4 bfr ds_reads, 8 MFMA}; GEN8s slotted between ----
#pragma unroll
        for (int sk = 0; sk < 4; ++sk) {
            int cph = ((sk * 2 + h5) ^ csw) * 8;
            f16x8 af0 = *(const f16x8*)&As2[cur][arow + cph];
            f16x8 af1 = *(const f16x8*)&As2[cur][arow + 2048 + cph];
            f16x8 bf0 = *(const f16x8*)&Bs[cur][brow + cph];
            f16x8 bf1 = *(const f16x8*)&Bs[cur][brow + 2048 + cph];
            f16x8 bf2 = *(const f16x8*)&Bs[cur][brow + 4096 + cph];
            f16x8 bf3 = *(const f16x8*)&Bs[cur][brow + 6144 + cph];
            acc[0][0] = __builtin_amdgcn_mfma_f32_32x32x16_f16(af0, bf0, acc[0][0], 0, 0, 0);
            acc[0][1] = __builtin_amdgcn_mfma_f32_32x32x16_f16(af0, bf1, acc[0][1], 0, 0, 0);
            acc[0][2] = __builtin_amdgcn_mfma_f32_32x32x16_f16(af0, bf2, acc[0][2], 0, 0, 0);
            acc[0][3] = __builtin_amdgcn_mfma_f32_32x32x16_f16(af0, bf3, acc[0][3], 0, 0, 0);
            acc[1][0] = __builtin_amdgcn_mfma_f32_32x32x16_f16(af1, bf0, acc[1][0], 0, 0, 0);
            acc[1][1] = __builtin_amdgcn_mfma_f32_32x32x16_f16(af1, bf1, acc[1][1], 0, 0, 0);
            acc[1][2] = __builtin_amdgcn_mfma_f32_32x32x16_f16(af1, bf2, acc[1][2], 0, 0, 0);
            acc[1][3] = __builtin_amdgcn_mfma_f32_32x32x16_f16(af1, bf3, acc[1][3], 0, 0, 0);
            if (t < 30) {
                if (sk == 1) { GEN8(q0, q1, wA); }   // weight-gen for t+2, first half
                if (sk == 2) { GEN8(q2, q3, wB); }   // second half
            }
        }
        __syncthreads();   // single drain per step: stage(t+1) has been in flight all step long
        cur ^= 1;
    }
    // row weight-sum: 4 threads (kq quads) per row -> quad reduce, one writer
    zacc += __shfl_xor(zacc, 1, 64);
    zacc += __shfl_xor(zacc, 2, 64);
    if ((tid & 3) == 0) g_Zp[(size_t)(h * 2 + ks) * NN + n0 + wn] = zacc;
    f16* O = g_oaccH + (size_t)(h * 2 + ks) * NN * FF;
#pragma unroll
    for (int it = 0; it < 2; ++it)
#pragma unroll
        for (int jt = 0; jt < 4; ++jt) {
            int f = wf * 128 + jt * 32 + c5;
#pragma unroll
            for (int qd = 0; qd < 4; ++qd) {
                int r0 = n0 + wr * 64 + it * 32 + qd * 8 + h5 * 4;
#pragma unroll
                for (int rr = 0; rr < 4; ++rr)
                    O[(size_t)(r0 + rr) * FF + f] = (f16)acc[it][jt][qd * 4 + rr];
            }
        }
}

// ---------------- final: out = relu(sum_h (0.25/Z_h[n]) * (slab_h0 + slab_h1)) ----------------
__global__ void k_reduce(float* __restrict__ out) {
    int t = blockIdx.x * 256 + threadIdx.x;   // 1024 blocks; 8 f-elems per thread, one row n
    size_t i = (size_t)t * 8;
    int n = t >> 6;                           // i / 512
    const size_t NF = (size_t)NN * FF;
    float s[8] = {0.f, 0.f, 0.f, 0.f, 0.f, 0.f, 0.f, 0.f};
#pragma unroll
    for (int h = 0; h < HH; ++h) {
        float Z = g_Zp[(size_t)(2 * h) * NN + n] + g_Zp[(size_t)(2 * h + 1) * NN + n];
        float sc = 0.25f / Z;
        f16x8 a = *(const f16x8*)(g_oaccH + (size_t)(2 * h) * NF + i);
        f16x8 bsl = *(const f16x8*)(g_oaccH + (size_t)(2 * h + 1) * NF + i);
#pragma unroll
        for (int rr = 0; rr < 8; ++rr) s[rr] += ((float)a[rr] + (float)bsl[rr]) * sc;
    }
    f32x4 o0, o1;
#pragma unroll
    for (int rr = 0; rr < 4; ++rr) o0[rr] = fmaxf(s[rr], 0.f);
#pragma unroll
    for (int rr = 0; rr < 4; ++rr) o1[rr] = fmaxf(s[4 + rr], 0.f);
    *(f32x4*)(out + i) = o0;
    *(f32x4*)(out + i + 4) = o1;
}

extern "C" void kernel_launch(void* const* d_in, const int* in_sizes, int n_in,
                              void* d_out, int out_size, void* d_ws, size_t ws_size,
                              hipStream_t stream) {
    (void)in_sizes; (void)n_in; (void)out_size; (void)d_ws; (void)ws_size;
    const float* nodes  = (const float*)d_in[0];
    const float* edges  = (const float*)d_in[1];
    const float* labels = (const float*)d_in[2];
    const float* We     = (const float*)d_in[3];
    const float* be     = (const float*)d_in[4];
    const float* W      = (const float*)d_in[5];
    const float* b      = (const float*)d_in[6];
    const float* u      = (const float*)d_in[7];
    const float* v      = (const float*)d_in[8];

    k_prep<<<PREP_CONV + PREP_TRAN + PREP_UV, 256, 0, stream>>>(nodes, edges, labels, We, W, be, b, u, v);
    k_pq<<<4096, 256, 0, stream>>>();
    k_gemm_feats<<<dim3(32, 4, 4), 256, 0, stream>>>();
    k_gemm_out<<<dim3(32, 4, 2), 512, 0, stream>>>();
    k_reduce<<<1024, 256, 0, stream>>>((float*)d_out);
}